// Round 2
// baseline (16494.089 us; speedup 1.0000x reference)
//
#include <hip/hip_runtime.h>
#include <hip/hip_bf16.h>

#define L_SEQ 4096
#define HDIM 2048
#define NPROJ 12352      // QKVZ + BA
#define QKVZ_ 12288
#define HK_ 16
#define HV_ 32
#define EPS_ 1e-6f

using bf16 = __hip_bfloat16;

__device__ __forceinline__ float b2f(bf16 x) { return __bfloat162float(x); }
__device__ __forceinline__ bf16 f2b(float x) { return __float2bfloat16(x); }

__device__ __forceinline__ float4 ld4(const float* p) { return *(const float4*)p; }
__device__ __forceinline__ float4 ld4(const bf16* p) {
  ushort4 u = *(const ushort4*)p;
  float4 r;
  r.x = __uint_as_float((unsigned)u.x << 16);
  r.y = __uint_as_float((unsigned)u.y << 16);
  r.z = __uint_as_float((unsigned)u.z << 16);
  r.w = __uint_as_float((unsigned)u.w << 16);
  return r;
}
__device__ __forceinline__ void st1(float* p, float v) { *p = v; }
__device__ __forceinline__ void st1(bf16* p, float v) { *p = f2b(v); }

// ---------------- tiled GEMM: C[M,N] = A[M,K] @ B[K,N], row-major ---------
// 64x64 tile, BK=16, 256 threads, 4x4 micro-tile per thread.
template <typename TA, typename TC>
__global__ __launch_bounds__(256) void gemm_t(
    const TA* __restrict__ A, const float* __restrict__ B,
    TC* __restrict__ C, int M, int N, int Kd) {
  __shared__ float As[16][68];  // As[k][m]
  __shared__ float Bs[16][68];  // Bs[k][n]
  const int tid = threadIdx.x;
  const int m0 = blockIdx.y * 64, n0 = blockIdx.x * 64;
  const int tx = tid & 15, ty = tid >> 4;
  const int la_m = tid >> 2, la_k = (tid & 3) << 2;
  const int lb_k = tid >> 4, lb_n = (tid & 15) << 2;
  float acc[4][4];
#pragma unroll
  for (int i = 0; i < 4; i++)
#pragma unroll
    for (int j = 0; j < 4; j++) acc[i][j] = 0.f;

  for (int k0 = 0; k0 < Kd; k0 += 16) {
    float4 a4 = ld4(&A[(size_t)(m0 + la_m) * Kd + k0 + la_k]);
    float4 b4 = ld4(&B[(size_t)(k0 + lb_k) * N + n0 + lb_n]);
    __syncthreads();
    As[la_k + 0][la_m] = a4.x;
    As[la_k + 1][la_m] = a4.y;
    As[la_k + 2][la_m] = a4.z;
    As[la_k + 3][la_m] = a4.w;
    *(float4*)&Bs[lb_k][lb_n] = b4;
    __syncthreads();
#pragma unroll
    for (int kk = 0; kk < 16; ++kk) {
      float4 av = *(const float4*)&As[kk][ty << 2];
      float4 bv = *(const float4*)&Bs[kk][tx << 2];
      float a_[4] = {av.x, av.y, av.z, av.w};
      float b_[4] = {bv.x, bv.y, bv.z, bv.w};
#pragma unroll
      for (int i = 0; i < 4; i++)
#pragma unroll
        for (int j = 0; j < 4; j++) acc[i][j] += a_[i] * b_[j];
    }
  }
#pragma unroll
  for (int i = 0; i < 4; i++)
#pragma unroll
    for (int j = 0; j < 4; j++)
      st1(&C[(size_t)(m0 + ty * 4 + i) * N + n0 + tx * 4 + j], acc[i][j]);
}

// ------- fused conv(K=4 causal) + SiLU + l2norm for q and k ---------------
// block = (t, hk), 128 threads (thread = dk).
__global__ __launch_bounds__(128) void conv_norm_qk(
    const bf16* __restrict__ proj, const float* __restrict__ conv_w,
    bf16* __restrict__ qn, bf16* __restrict__ kn) {
  const int t = blockIdx.x >> 4, hk = blockIdx.x & 15;
  const int d = threadIdx.x;
  const int cq = hk * 128 + d;         // q channel in mixed_qkv
  const int ck = 2048 + hk * 128 + d;  // k channel
  const int colq = hk * 768 + d;       // proj column for q
  const int colk = colq + 128;         // proj column for k
  float sq = 0.f, sk = 0.f;
#pragma unroll
  for (int j = 0; j < 4; j++) {
    int ts = t + j - 3;
    if (ts >= 0) {
      sq += conv_w[cq * 4 + j] * b2f(proj[(size_t)ts * NPROJ + colq]);
      sk += conv_w[ck * 4 + j] * b2f(proj[(size_t)ts * NPROJ + colk]);
    }
  }
  // silu
  float qv = sq / (1.f + expf(-sq));
  float kv = sk / (1.f + expf(-sk));
  // block l2-norm over 128 lanes (2 waves)
  float ssq = qv * qv, ssk = kv * kv;
#pragma unroll
  for (int off = 32; off > 0; off >>= 1) {
    ssq += __shfl_down(ssq, off, 64);
    ssk += __shfl_down(ssk, off, 64);
  }
  __shared__ float red[4];
  if ((d & 63) == 0) {
    red[(d >> 6) * 2] = ssq;
    red[(d >> 6) * 2 + 1] = ssk;
  }
  __syncthreads();
  float sumq = red[0] + red[2];
  float sumk = red[1] + red[3];
  size_t o = (size_t)(t * 16 + hk) * 128 + d;
  qn[o] = f2b(qv * rsqrtf(sumq + EPS_) * 0.08838834764831845f);  // * DK^-0.5
  kn[o] = f2b(kv * rsqrtf(sumk + EPS_));
}

// ------- conv + SiLU for v channels ---------------------------------------
__global__ __launch_bounds__(256) void conv_silu_v(
    const bf16* __restrict__ proj, const float* __restrict__ conv_w,
    bf16* __restrict__ vbuf) {
  int idx = blockIdx.x * 256 + threadIdx.x;  // t*4096 + c
  int t = idx >> 12, c = idx & 4095;
  int hv = c >> 7, d = c & 127;
  int chan = 4096 + c;  // mixed_qkv channel
  int col = (hv >> 1) * 768 + 256 + (hv & 1) * 128 + d;
  float s = 0.f;
#pragma unroll
  for (int j = 0; j < 4; j++) {
    int ts = t + j - 3;
    if (ts >= 0) s += conv_w[chan * 4 + j] * b2f(proj[(size_t)ts * NPROJ + col]);
  }
  vbuf[idx] = f2b(s / (1.f + expf(-s)));
}

// ---------------- beta / g ------------------------------------------------
__global__ __launch_bounds__(256) void compute_bg(
    const bf16* __restrict__ proj, const float* __restrict__ A_log,
    const float* __restrict__ dt_bias, float* __restrict__ beta_arr,
    float* __restrict__ g_arr) {
  int idx = blockIdx.x * 256 + threadIdx.x;  // t*32 + hv
  int t = idx >> 5, hv = idx & 31;
  size_t base = (size_t)t * NPROJ + QKVZ_ + (hv >> 1) * 4 + (hv & 1);
  float b = b2f(proj[base]);
  float a = b2f(proj[base + 2]);
  beta_arr[idx] = 1.f / (1.f + expf(-b));
  float x = a + dt_bias[hv];
  float sp = (x > 20.f) ? x : log1pf(expf(x));
  g_arr[idx] = -expf(A_log[hv]) * sp;
}

// ---------------- sequential delta-rule scan ------------------------------
// 32 blocks (one per value head), 128 threads (thread = dv column).
// S[dk] kept in 128 VGPRs per thread. attn written in-place over vbuf.
__global__ __launch_bounds__(128) void scan_kernel(
    const bf16* __restrict__ qn, const bf16* __restrict__ kn,
    bf16* __restrict__ vbuf, const bf16* __restrict__ proj,
    const float* __restrict__ beta_arr, const float* __restrict__ g_arr,
    const float* __restrict__ norm_w) {
  const int h = blockIdx.x;    // 0..31
  const int dv = threadIdx.x;  // 0..127
  const int hk = h >> 1;
  __shared__ float lds_k[128];
  __shared__ float lds_q[128];
  __shared__ float partial[2];
  float S[128];
#pragma unroll
  for (int i = 0; i < 128; i++) S[i] = 0.f;
  const int zcol = hk * 768 + 512 + (h & 1) * 128;
  const float nw = norm_w[dv];

  for (int t = 0; t < L_SEQ; t++) {
    float kv = b2f(kn[(size_t)(t * 16 + hk) * 128 + dv]);
    float qv = b2f(qn[(size_t)(t * 16 + hk) * 128 + dv]);
    float vv = b2f(vbuf[(size_t)t * 4096 + h * 128 + dv]);
    float zv = b2f(proj[(size_t)t * NPROJ + zcol + dv]);
    float gt = g_arr[t * 32 + h];
    float bt = beta_arr[t * 32 + h];
    float eg = expf(gt);
    __syncthreads();  // previous step's LDS reads done
    lds_k[dv] = kv;
    lds_q[dv] = qv;
    __syncthreads();

    float kS0 = 0, kS1 = 0, kS2 = 0, kS3 = 0;
    float qS0 = 0, qS1 = 0, qS2 = 0, qS3 = 0;
    float qk0 = 0, qk1 = 0, qk2 = 0, qk3 = 0;
#pragma unroll
    for (int dk = 0; dk < 128; dk += 4) {
      float4 k4 = *(const float4*)&lds_k[dk];
      float4 q4 = *(const float4*)&lds_q[dk];
      kS0 += k4.x * S[dk + 0];
      kS1 += k4.y * S[dk + 1];
      kS2 += k4.z * S[dk + 2];
      kS3 += k4.w * S[dk + 3];
      qS0 += q4.x * S[dk + 0];
      qS1 += q4.y * S[dk + 1];
      qS2 += q4.z * S[dk + 2];
      qS3 += q4.w * S[dk + 3];
      qk0 += q4.x * k4.x;
      qk1 += q4.y * k4.y;
      qk2 += q4.z * k4.z;
      qk3 += q4.w * k4.w;
    }
    float kS = (kS0 + kS1) + (kS2 + kS3);
    float qS = (qS0 + qS1) + (qS2 + qS3);
    float qk = (qk0 + qk1) + (qk2 + qk3);

    float delta = (vv - eg * kS) * bt;
    float o = eg * qS + qk * delta;

#pragma unroll
    for (int dk = 0; dk < 128; dk += 4) {
      float4 k4 = *(const float4*)&lds_k[dk];
      S[dk + 0] = eg * S[dk + 0] + k4.x * delta;
      S[dk + 1] = eg * S[dk + 1] + k4.y * delta;
      S[dk + 2] = eg * S[dk + 2] + k4.z * delta;
      S[dk + 3] = eg * S[dk + 3] + k4.w * delta;
    }

    // fused RMS-norm over dv + norm_w + silu(z) gate
    float ss = o * o;
#pragma unroll
    for (int off = 32; off > 0; off >>= 1) ss += __shfl_down(ss, off, 64);
    if ((dv & 63) == 0) partial[dv >> 6] = ss;
    __syncthreads();
    float var = (partial[0] + partial[1]) * (1.f / 128.f);
    float core = o * rsqrtf(var + EPS_) * nw;
    core *= zv / (1.f + expf(-zv));  // * silu(z)
    vbuf[(size_t)t * 4096 + h * 128 + dv] = f2b(core);  // attn, in-place
  }
}

extern "C" void kernel_launch(void* const* d_in, const int* in_sizes, int n_in,
                              void* d_out, int out_size, void* d_ws,
                              size_t ws_size, hipStream_t stream) {
  const float* hidden = (const float*)d_in[0];
  const float* in_w = (const float*)d_in[1];
  const float* conv_w = (const float*)d_in[2];
  const float* A_log = (const float*)d_in[3];
  const float* dt_bias = (const float*)d_in[4];
  const float* norm_w = (const float*)d_in[5];
  const float* out_w = (const float*)d_in[6];
  float* out = (float*)d_out;

  // workspace layout (bytes): total 169,345,024 B (~161.5 MB)
  char* p = (char*)d_ws;
  bf16* proj = (bf16*)p;            p += (size_t)L_SEQ * NPROJ * 2;   // 101,187,584
  bf16* qn   = (bf16*)p;            p += (size_t)L_SEQ * 2048 * 2;    //  16,777,216
  bf16* kn   = (bf16*)p;            p += (size_t)L_SEQ * 2048 * 2;    //  16,777,216
  bf16* vbuf = (bf16*)p;            p += (size_t)L_SEQ * 4096 * 2;    //  33,554,432 (v, then attn)
  float* beta = (float*)p;          p += (size_t)L_SEQ * 32 * 4;      //     524,288
  float* g    = (float*)p;          p += (size_t)L_SEQ * 32 * 4;      //     524,288

  // 1. in_proj GEMM  (4096 x 12352) = (4096 x 2048) @ (2048 x 12352), bf16 out
  gemm_t<float, bf16><<<dim3(NPROJ / 64, L_SEQ / 64), 256, 0, stream>>>(
      hidden, in_w, proj, L_SEQ, NPROJ, HDIM);
  // 2. fused conv + silu + l2norm for q,k
  conv_norm_qk<<<L_SEQ * HK_, 128, 0, stream>>>(proj, conv_w, qn, kn);
  // 3. conv + silu for v
  conv_silu_v<<<(L_SEQ * 4096) / 256, 256, 0, stream>>>(proj, conv_w, vbuf);
  // 4. beta / g
  compute_bg<<<(L_SEQ * HV_) / 256, 256, 0, stream>>>(proj, A_log, dt_bias,
                                                      beta, g);
  // 5. sequential scan + fused gated RMSNorm (attn overwrites vbuf)
  scan_kernel<<<HV_, 128, 0, stream>>>(qn, kn, vbuf, proj, beta, g, norm_w);
  // 6. out_proj GEMM (4096 x 2048) = (4096 x 4096) @ (4096 x 2048), fp32 out
  gemm_t<bf16, float><<<dim3(2048 / 64, L_SEQ / 64), 256, 0, stream>>>(
      vbuf, out_w, out, L_SEQ, 2048, 4096);
}

// Round 3
// 8300.625 us; speedup vs baseline: 1.9871x; 1.9871x over previous
//
#include <hip/hip_runtime.h>
#include <hip/hip_bf16.h>

#define L_SEQ 4096
#define HDIM 2048
#define NPROJ 12352      // QKVZ + BA
#define QKVZ_ 12288
#define EPS_ 1e-6f

using bf16 = __hip_bfloat16;
typedef __attribute__((ext_vector_type(8))) short short8;
typedef __attribute__((ext_vector_type(4))) float f32x4;

__device__ __forceinline__ float b2f(bf16 x) { return __bfloat162float(x); }
__device__ __forceinline__ bf16 f2b(float x) { return __float2bfloat16(x); }

__device__ __forceinline__ void async_copy16(const void* g, void* l) {
  __builtin_amdgcn_global_load_lds(
      (const __attribute__((address_space(1))) void*)g,
      (__attribute__((address_space(3))) void*)l, 16, 0, 0);
}

// ---------------- fp32 -> bf16 convert (linear) ---------------------------
__global__ __launch_bounds__(256) void cvt_bf16(const float* __restrict__ in,
                                                bf16* __restrict__ outp) {
  int i = (blockIdx.x * 256 + threadIdx.x) * 4;
  float4 v = *(const float4*)&in[i];
  bf16 o4[4] = {f2b(v.x), f2b(v.y), f2b(v.z), f2b(v.w)};
  *(ushort4*)&outp[i] = *(ushort4*)o4;
}

// ---------------- MFMA bf16 GEMM: C[M,N] = A[M,K](bf16) @ B[K,N](fp32) ----
// 128x128 tile, BK=32, 256 threads (4 waves in 2x2), 16x16x32 MFMA.
template <bool CBF16>
__global__ __launch_bounds__(256) void gemm_mfma(
    const bf16* __restrict__ A, const float* __restrict__ B, void* __restrict__ Cv,
    int M, int N, int Kd) {
  __shared__ bf16 As[128 * 32];      // [m][k] row-major, 8 KB
  __shared__ bf16 Bs[4 * 128 * 8];   // [q][n][j]: B[k0+q*8+j][n0+n], 8 KB
  const int tid = threadIdx.x;
  const int wave = tid >> 6, lane = tid & 63;
  const int l15 = lane & 15, quad = lane >> 4;
  const int m0 = blockIdx.y * 128, n0 = blockIdx.x * 128;
  const int mw = (wave >> 1) * 64, nw = (wave & 1) * 64;

  f32x4 acc[4][4];
#pragma unroll
  for (int i = 0; i < 4; i++)
#pragma unroll
    for (int j = 0; j < 4; j++) acc[i][j] = {0.f, 0.f, 0.f, 0.f};

  // A staging: chunk c = tid, tid+256 ; m = c>>2, k8 = c&3 (16B per chunk)
  const bf16* a_src0 = A + (size_t)(m0 + (tid >> 2)) * Kd + (tid & 3) * 8;
  const bf16* a_src1 = A + (size_t)(m0 + 64 + (tid >> 2)) * Kd + (tid & 3) * 8;
  bf16* a_dst0 = &As[tid * 8];
  bf16* a_dst1 = &As[(tid + 256) * 8];
  // B staging: q = wave, n = lane and lane+64
  int bc0 = n0 + lane, bc1 = n0 + 64 + lane;
  bc0 = bc0 < N ? bc0 : N - 1;  // clamp for N % 128 != 0 (stores guarded)
  bc1 = bc1 < N ? bc1 : N - 1;

  for (int k0 = 0; k0 < Kd; k0 += 32) {
    // B global loads (fp32, coalesced 256B/inst)
    float bv0[8], bv1[8];
#pragma unroll
    for (int j = 0; j < 8; j++) {
      const float* brow = B + (size_t)(k0 + wave * 8 + j) * N;
      bv0[j] = brow[bc0];
      bv1[j] = brow[bc1];
    }
    __syncthreads();  // previous iteration's frag reads done
    async_copy16(a_src0 + k0, a_dst0);
    async_copy16(a_src1 + k0, a_dst1);
    bf16 bb0[8], bb1[8];
#pragma unroll
    for (int j = 0; j < 8; j++) { bb0[j] = f2b(bv0[j]); bb1[j] = f2b(bv1[j]); }
    *(float4*)&Bs[(wave * 128 + lane) * 8] = *(float4*)bb0;
    *(float4*)&Bs[(wave * 128 + 64 + lane) * 8] = *(float4*)bb1;
    __syncthreads();  // staged data visible (compiler drains vmcnt+lgkm)

    short8 af[4], bf[4];
#pragma unroll
    for (int i = 0; i < 4; i++)
      af[i] = *(const short8*)&As[(mw + i * 16 + l15) * 32 + quad * 8];
#pragma unroll
    for (int j = 0; j < 4; j++)
      bf[j] = *(const short8*)&Bs[(quad * 128 + nw + j * 16 + l15) * 8];
#pragma unroll
    for (int i = 0; i < 4; i++)
#pragma unroll
      for (int j = 0; j < 4; j++)
        acc[i][j] = __builtin_amdgcn_mfma_f32_16x16x32_bf16(af[i], bf[j],
                                                            acc[i][j], 0, 0, 0);
  }

  // epilogue: D row = quad*4 + reg, col = l15 (per 16x16 block)
#pragma unroll
  for (int i = 0; i < 4; i++) {
#pragma unroll
    for (int j = 0; j < 4; j++) {
      int col = n0 + nw + j * 16 + l15;
      if (col < N) {
#pragma unroll
        for (int r = 0; r < 4; r++) {
          int row = m0 + mw + i * 16 + quad * 4 + r;
          if (CBF16)
            ((bf16*)Cv)[(size_t)row * N + col] = f2b(acc[i][j][r]);
          else
            ((float*)Cv)[(size_t)row * N + col] = acc[i][j][r];
        }
      }
    }
  }
}

// ------- fused conv(K=4 causal) + SiLU + l2norm for q and k ---------------
__global__ __launch_bounds__(128) void conv_norm_qk(
    const bf16* __restrict__ proj, const float* __restrict__ conv_w,
    bf16* __restrict__ qn, bf16* __restrict__ kn) {
  const int t = blockIdx.x >> 4, hk = blockIdx.x & 15;
  const int d = threadIdx.x;
  const int cq = hk * 128 + d;
  const int ck = 2048 + hk * 128 + d;
  const int colq = hk * 768 + d;
  const int colk = colq + 128;
  float sq = 0.f, sk = 0.f;
#pragma unroll
  for (int j = 0; j < 4; j++) {
    int ts = t + j - 3;
    if (ts >= 0) {
      sq += conv_w[cq * 4 + j] * b2f(proj[(size_t)ts * NPROJ + colq]);
      sk += conv_w[ck * 4 + j] * b2f(proj[(size_t)ts * NPROJ + colk]);
    }
  }
  float qv = sq / (1.f + expf(-sq));
  float kv = sk / (1.f + expf(-sk));
  float ssq = qv * qv, ssk = kv * kv;
#pragma unroll
  for (int off = 32; off > 0; off >>= 1) {
    ssq += __shfl_down(ssq, off, 64);
    ssk += __shfl_down(ssk, off, 64);
  }
  __shared__ float red[4];
  if ((d & 63) == 0) {
    red[(d >> 6) * 2] = ssq;
    red[(d >> 6) * 2 + 1] = ssk;
  }
  __syncthreads();
  float sumq = red[0] + red[2];
  float sumk = red[1] + red[3];
  size_t o = (size_t)(t * 16 + hk) * 128 + d;
  qn[o] = f2b(qv * rsqrtf(sumq + EPS_) * 0.08838834764831845f);
  kn[o] = f2b(kv * rsqrtf(sumk + EPS_));
}

// ------- conv + SiLU for v channels ---------------------------------------
__global__ __launch_bounds__(256) void conv_silu_v(
    const bf16* __restrict__ proj, const float* __restrict__ conv_w,
    bf16* __restrict__ vbuf) {
  int idx = blockIdx.x * 256 + threadIdx.x;
  int t = idx >> 12, c = idx & 4095;
  int hv = c >> 7, d = c & 127;
  int chan = 4096 + c;
  int col = (hv >> 1) * 768 + 256 + (hv & 1) * 128 + d;
  float s = 0.f;
#pragma unroll
  for (int j = 0; j < 4; j++) {
    int ts = t + j - 3;
    if (ts >= 0) s += conv_w[chan * 4 + j] * b2f(proj[(size_t)ts * NPROJ + col]);
  }
  vbuf[idx] = f2b(s / (1.f + expf(-s)));
}

// ---------------- beta / g ------------------------------------------------
__global__ __launch_bounds__(256) void compute_bg(
    const bf16* __restrict__ proj, const float* __restrict__ A_log,
    const float* __restrict__ dt_bias, float* __restrict__ beta_arr,
    float* __restrict__ g_arr) {
  int idx = blockIdx.x * 256 + threadIdx.x;
  int t = idx >> 5, hv = idx & 31;
  size_t base = (size_t)t * NPROJ + QKVZ_ + (hv >> 1) * 4 + (hv & 1);
  float b = b2f(proj[base]);
  float a = b2f(proj[base + 2]);
  beta_arr[idx] = 1.f / (1.f + expf(-b));
  float x = a + dt_bias[hv];
  float sp = (x > 20.f) ? x : log1pf(expf(x));
  g_arr[idx] = -expf(A_log[hv]) * sp;
}

// ---------------- sequential delta-rule scan, 4-way dk split --------------
// 32 blocks (one per value head), 512 threads: (quarter, dv), S[32]/thread.
__global__ __launch_bounds__(512) void scan_kernel(
    const bf16* __restrict__ qn, const bf16* __restrict__ kn,
    bf16* __restrict__ vbuf, const bf16* __restrict__ proj,
    const float* __restrict__ beta_arr, const float* __restrict__ g_arr,
    const float* __restrict__ norm_w) {
  const int h = blockIdx.x, hk = h >> 1;
  const int tid = threadIdx.x;
  const int quarter = tid >> 7, dv = tid & 127;
  const int dk0 = quarter * 32;
  __shared__ float lds_k[128], lds_q[128];
  __shared__ float red_kS[4][128], red_qS[4][128], red_qk[4][128];
  __shared__ float partial2[2];
  float S[32];
#pragma unroll
  for (int i = 0; i < 32; i++) S[i] = 0.f;
  const int zcol = hk * 768 + 512 + (h & 1) * 128;
  const float nw_ = norm_w[dv];
  const bf16* kq_base = (quarter == 0) ? kn : qn;

  // prologue: load t=0
  float kqv = (quarter < 2) ? b2f(kq_base[(size_t)hk * 128 + dv]) : 0.f;
  float vv = b2f(vbuf[(size_t)h * 128 + dv]);
  float zv = (quarter == 0) ? b2f(proj[(size_t)zcol + dv]) : 0.f;
  float gt = g_arr[h], bt = beta_arr[h];

  for (int t = 0; t < L_SEQ; t++) {
    float eg = expf(gt);
    float vv_c = vv, bt_c = bt, zv_c = zv;
    if (quarter == 0) lds_k[dv] = kqv;
    else if (quarter == 1) lds_q[dv] = kqv;
    __syncthreads();  // (B) staged k/q visible

    // prefetch t+1 while compute fills the latency
    int tn = (t + 1 < L_SEQ) ? t + 1 : L_SEQ - 1;
    if (quarter < 2) kqv = b2f(kq_base[(size_t)(tn * 16 + hk) * 128 + dv]);
    vv = b2f(vbuf[(size_t)tn * 4096 + h * 128 + dv]);
    if (quarter == 0) zv = b2f(proj[(size_t)tn * NPROJ + zcol + dv]);
    gt = g_arr[tn * 32 + h];
    bt = beta_arr[tn * 32 + h];

    // partial dots over this quarter's 32 dk (2 chains each for ILP)
    float kA = 0, kB = 0, qA = 0, qB = 0, pA = 0, pB = 0;
#pragma unroll
    for (int i = 0; i < 32; i += 8) {
      float4 k4 = *(const float4*)&lds_k[dk0 + i];
      float4 q4 = *(const float4*)&lds_q[dk0 + i];
      float4 k5 = *(const float4*)&lds_k[dk0 + i + 4];
      float4 q5 = *(const float4*)&lds_q[dk0 + i + 4];
      kA += k4.x * S[i] + k4.y * S[i + 1] + k4.z * S[i + 2] + k4.w * S[i + 3];
      kB += k5.x * S[i + 4] + k5.y * S[i + 5] + k5.z * S[i + 6] + k5.w * S[i + 7];
      qA += q4.x * S[i] + q4.y * S[i + 1] + q4.z * S[i + 2] + q4.w * S[i + 3];
      qB += q5.x * S[i + 4] + q5.y * S[i + 5] + q5.z * S[i + 6] + q5.w * S[i + 7];
      pA += q4.x * k4.x + q4.y * k4.y + q4.z * k4.z + q4.w * k4.w;
      pB += q5.x * k5.x + q5.y * k5.y + q5.z * k5.z + q5.w * k5.w;
    }
    red_kS[quarter][dv] = kA + kB;
    red_qS[quarter][dv] = qA + qB;
    red_qk[quarter][dv] = pA + pB;
    __syncthreads();  // (C) partials visible

    float kS = red_kS[0][dv] + red_kS[1][dv] + red_kS[2][dv] + red_kS[3][dv];
    float qS = red_qS[0][dv] + red_qS[1][dv] + red_qS[2][dv] + red_qS[3][dv];
    float qk = red_qk[0][dv] + red_qk[1][dv] + red_qk[2][dv] + red_qk[3][dv];
    float delta = (vv_c - eg * kS) * bt_c;
    float o = eg * qS + qk * delta;

#pragma unroll
    for (int i = 0; i < 32; i += 4) {
      float4 k4 = *(const float4*)&lds_k[dk0 + i];
      S[i] = eg * S[i] + k4.x * delta;
      S[i + 1] = eg * S[i + 1] + k4.y * delta;
      S[i + 2] = eg * S[i + 2] + k4.z * delta;
      S[i + 3] = eg * S[i + 3] + k4.w * delta;
    }

    if (quarter == 0) {
      float ss = o * o;
#pragma unroll
      for (int off = 32; off > 0; off >>= 1) ss += __shfl_down(ss, off, 64);
      if ((tid & 63) == 0) partial2[tid >> 6] = ss;
    }
    __syncthreads();  // (D) o^2 partials visible; doubles as LDS-reuse barrier

    if (quarter == 0) {
      float var = (partial2[0] + partial2[1]) * (1.f / 128.f);
      float core = o * rsqrtf(var + EPS_) * nw_;
      core *= zv_c / (1.f + expf(-zv_c));
      vbuf[(size_t)t * 4096 + h * 128 + dv] = f2b(core);
    }
  }
}

extern "C" void kernel_launch(void* const* d_in, const int* in_sizes, int n_in,
                              void* d_out, int out_size, void* d_ws,
                              size_t ws_size, hipStream_t stream) {
  const float* hidden = (const float*)d_in[0];
  const float* in_w = (const float*)d_in[1];
  const float* conv_w = (const float*)d_in[2];
  const float* A_log = (const float*)d_in[3];
  const float* dt_bias = (const float*)d_in[4];
  const float* norm_w = (const float*)d_in[5];
  const float* out_w = (const float*)d_in[6];
  float* out = (float*)d_out;

  // workspace layout: total 169,345,024 B (proven size)
  char* p = (char*)d_ws;
  bf16* proj = (bf16*)p;   p += (size_t)L_SEQ * NPROJ * 2;  // 101,187,584
  bf16* vbuf = (bf16*)p;   p += (size_t)L_SEQ * 4096 * 2;   //  33,554,432
  float* beta = (float*)p; p += (size_t)L_SEQ * 32 * 4;     //     524,288
  float* g = (float*)p;    p += (size_t)L_SEQ * 32 * 4;     //     524,288
  bf16* qn = (bf16*)p;     // 16,777,216
  bf16* kn = qn + (size_t)L_SEQ * 2048;  // 16,777,216
  bf16* hb16 = qn;  // aliases qn region; dead before conv_norm_qk writes qn

  // 0. hidden fp32 -> bf16
  cvt_bf16<<<(L_SEQ * HDIM) / 1024, 256, 0, stream>>>(hidden, hb16);
  // 1. in_proj GEMM (MFMA): (4096 x 12352) = (4096 x 2048) @ (2048 x 12352)
  gemm_mfma<true><<<dim3(97, 32), 256, 0, stream>>>(hb16, in_w, proj, L_SEQ,
                                                    NPROJ, HDIM);
  // 2. fused conv + silu + l2norm for q,k
  conv_norm_qk<<<L_SEQ * 16, 128, 0, stream>>>(proj, conv_w, qn, kn);
  // 3. conv + silu for v
  conv_silu_v<<<(L_SEQ * 4096) / 256, 256, 0, stream>>>(proj, conv_w, vbuf);
  // 4. beta / g
  compute_bg<<<(L_SEQ * 32) / 256, 256, 0, stream>>>(proj, A_log, dt_bias,
                                                     beta, g);
  // 5. sequential scan + fused gated RMSNorm (attn overwrites vbuf)
  scan_kernel<<<32, 512, 0, stream>>>(qn, kn, vbuf, proj, beta, g, norm_w);
  // 6. out_proj GEMM (MFMA): (4096 x 2048) = (4096 x 4096) @ (4096 x 2048)
  gemm_mfma<false><<<dim3(16, 32), 256, 0, stream>>>(vbuf, out_w, out, L_SEQ,
                                                     2048, 4096);
}